// Round 11
// baseline (320.812 us; speedup 1.0000x reference)
//
#include <hip/hip_runtime.h>
#include <hip/hip_bf16.h>

#define BB 256
#define AA 512
#define DD 200
#define ADIM 600
#define NKC 4
#define KCH 150   // 600 / 4

// ws layout (floats):
//   X1       at 0        (256*600  = 153600)
//   parts    at 153600   (4*256*600 = 614400)
//   X2       at 768000   (256*600  = 153600)
//   logits   at 921600   (256*512  = 131072)
//   counters at 1052672  (256 ints)

// X1 = relu(obs @ W1 + b1). 128 blocks, 2 rows each, 320 threads.
// Block 0 additionally zeroes the per-row finisher counters (stream-ordered
// before k_logits, so this re-arms the fused softmax every graph replay).
__global__ __launch_bounds__(320) void k_x1(const float* __restrict__ obs,
                                            const float* __restrict__ W1,
                                            const float* __restrict__ b1,
                                            float* __restrict__ X1,
                                            int* __restrict__ counters) {
  __shared__ __align__(16) float s_obs[2 * DD];
  const int rb = blockIdx.x * 2;  // first of 2 rows
  const int tid = threadIdx.x;
  if (blockIdx.x == 0 && tid < BB) counters[tid] = 0;
  if (tid < 100) {  // 2*200 floats = 100 float4, contiguous rows
    reinterpret_cast<float4*>(s_obs)[tid] =
        reinterpret_cast<const float4*>(obs + rb * DD)[tid];
  }
  __syncthreads();

  const int jp = tid;
  if (jp < 300) {
    const int j0 = 2 * jp;
    float a00 = 0.f, a01 = 0.f, a10 = 0.f, a11 = 0.f;
#pragma unroll 5
    for (int kq = 0; kq < 50; ++kq) {
      const float4 x0 = *reinterpret_cast<const float4*>(&s_obs[kq * 4]);
      const float4 x1 = *reinterpret_cast<const float4*>(&s_obs[DD + kq * 4]);
      const float* wb = W1 + (kq * 4) * ADIM + j0;
      const float2 w0 = *reinterpret_cast<const float2*>(wb);
      const float2 w1 = *reinterpret_cast<const float2*>(wb + ADIM);
      const float2 w2 = *reinterpret_cast<const float2*>(wb + 2 * ADIM);
      const float2 w3 = *reinterpret_cast<const float2*>(wb + 3 * ADIM);
      a00 = fmaf(x0.x, w0.x, a00); a01 = fmaf(x0.x, w0.y, a01);
      a10 = fmaf(x1.x, w0.x, a10); a11 = fmaf(x1.x, w0.y, a11);
      a00 = fmaf(x0.y, w1.x, a00); a01 = fmaf(x0.y, w1.y, a01);
      a10 = fmaf(x1.y, w1.x, a10); a11 = fmaf(x1.y, w1.y, a11);
      a00 = fmaf(x0.z, w2.x, a00); a01 = fmaf(x0.z, w2.y, a01);
      a10 = fmaf(x1.z, w2.x, a10); a11 = fmaf(x1.z, w2.y, a11);
      a00 = fmaf(x0.w, w3.x, a00); a01 = fmaf(x0.w, w3.y, a01);
      a10 = fmaf(x1.w, w3.x, a10); a11 = fmaf(x1.w, w3.y, a11);
    }
    const float2 bv = *reinterpret_cast<const float2*>(b1 + j0);
    float2 o0, o1;
    o0.x = fmaxf(a00 + bv.x, 0.f); o0.y = fmaxf(a01 + bv.y, 0.f);
    o1.x = fmaxf(a10 + bv.x, 0.f); o1.y = fmaxf(a11 + bv.y, 0.f);
    *reinterpret_cast<float2*>(X1 + rb * ADIM + j0) = o0;
    *reinterpret_cast<float2*>(X1 + (rb + 1) * ADIM + j0) = o1;
  }
}

// parts[kc][row][j] = X1[row][kc-chunk] @ W2[kc-chunk][j].
__global__ __launch_bounds__(640) void k_x2p(const float* __restrict__ X1,
                                             const float* __restrict__ W2,
                                             float* __restrict__ parts) {
  __shared__ __align__(16) float s_x1[4 * 152];  // 150 used, stride 152
  const int rg = blockIdx.x >> 2;
  const int kc = blockIdx.x & 3;
  const int tid = threadIdx.x;
  const int kbase = kc * KCH;

  for (int idx = tid; idx < 4 * KCH; idx += 640) {
    const int r = idx / KCH, c = idx % KCH;
    s_x1[r * 152 + c] = X1[(rg * 4 + r) * ADIM + kbase + c];
  }
  __syncthreads();

  const int j = tid;
  if (j < ADIM) {
    float acc0 = 0.f, acc1 = 0.f, acc2 = 0.f, acc3 = 0.f;
#pragma unroll 4
    for (int kq = 0; kq < 37; ++kq) {  // 37*4 = 148 of 150
      const int k4 = kq * 4;
      const float4 x0 = *reinterpret_cast<const float4*>(&s_x1[0 * 152 + k4]);
      const float4 x1 = *reinterpret_cast<const float4*>(&s_x1[1 * 152 + k4]);
      const float4 x2 = *reinterpret_cast<const float4*>(&s_x1[2 * 152 + k4]);
      const float4 x3 = *reinterpret_cast<const float4*>(&s_x1[3 * 152 + k4]);
      const float* wb = W2 + (size_t)(kbase + k4) * ADIM + j;
      const float w0 = wb[0];
      const float w1 = wb[ADIM];
      const float w2 = wb[2 * ADIM];
      const float w3 = wb[3 * ADIM];
      acc0 = fmaf(x0.x, w0, fmaf(x0.y, w1, fmaf(x0.z, w2, fmaf(x0.w, w3, acc0))));
      acc1 = fmaf(x1.x, w0, fmaf(x1.y, w1, fmaf(x1.z, w2, fmaf(x1.w, w3, acc1))));
      acc2 = fmaf(x2.x, w0, fmaf(x2.y, w1, fmaf(x2.z, w2, fmaf(x2.w, w3, acc2))));
      acc3 = fmaf(x3.x, w0, fmaf(x3.y, w1, fmaf(x3.z, w2, fmaf(x3.w, w3, acc3))));
    }
#pragma unroll
    for (int kk = 148; kk < KCH; ++kk) {
      const float w = W2[(size_t)(kbase + kk) * ADIM + j];
      acc0 = fmaf(s_x1[0 * 152 + kk], w, acc0);
      acc1 = fmaf(s_x1[1 * 152 + kk], w, acc1);
      acc2 = fmaf(s_x1[2 * 152 + kk], w, acc2);
      acc3 = fmaf(s_x1[3 * 152 + kk], w, acc3);
    }
    float* pb = parts + (size_t)kc * (BB * ADIM) + (rg * 4) * ADIM + j;
    pb[0] = acc0;
    pb[ADIM] = acc1;
    pb[2 * ADIM] = acc2;
    pb[3 * ADIM] = acc3;
  }
}

// Finalize X2 = b2 + sum_kc parts. One block per batch row.
__global__ __launch_bounds__(640) void k_x2(const float* __restrict__ parts,
                                            const float* __restrict__ b2,
                                            float* __restrict__ X2) {
  const int b = blockIdx.x;
  const int j = threadIdx.x;
  if (j < ADIM) {
    float v = b2[j];
#pragma unroll
    for (int kc = 0; kc < NKC; ++kc)
      v += parts[(size_t)kc * (BB * ADIM) + b * ADIM + j];
    X2[b * ADIM + j] = v;
  }
}

// In-row (16-lane) rotate-add (DPP), no LDS-pipe traffic.
template <int CTRL>
__device__ inline float rot_add(float x) {
  const int xi = __float_as_int(x);
  const int r = __builtin_amdgcn_update_dpp(0, xi, CTRL, 0xF, 0xF, false);
  return x + __int_as_float(r);
}

// Gather (identical geometry to r10) + fused last-block softmax.
// 8 blocks per batch row write their 64 logits to ws; the 8th block to
// arrive (per-row atomic counter) re-reads the row and computes softmax +
// entropy in-block. Output is deterministic: arrival order only selects the
// worker, the math reads the complete, fenced logits row.
__global__ __launch_bounds__(256, 6) void k_logits_soft(
    const float* __restrict__ X2, const float* __restrict__ rel,
    const float* __restrict__ entt, const float* __restrict__ trip,
    const int* __restrict__ r_sp, const int* __restrict__ e_sp,
    const int* __restrict__ t_id, const int* __restrict__ amask,
    float* __restrict__ logits, int* __restrict__ counters,
    float* __restrict__ out_dist, float* __restrict__ out_ent) {
  __shared__ float s_red[4];
  __shared__ int s_last;
  const int tid = threadIdx.x;
  const int b = blockIdx.x >> 3;
  const int c = blockIdx.x & 7;
  const int w = tid >> 6;
  const int lane = tid & 63;
  const int base = b * AA + c * 64 + w * 16;  // first of this wave's 16 actions

  // X2 segments -> registers; lane l holds floats [4l,4l+4) of each segment.
  float4 xr = {0.f, 0.f, 0.f, 0.f}, xe = xr, xt = xr;
  if (lane < 50) {
    const float* x2row = X2 + b * ADIM;
    xr = *reinterpret_cast<const float4*>(x2row + 4 * lane);
    xe = *reinterpret_cast<const float4*>(x2row + DD + 4 * lane);
    xt = *reinterpret_cast<const float4*>(x2row + 2 * DD + 4 * lane);
  }

  // indices + mask for the wave's 16 actions, replicated across lanes
  const int q = lane & 15;
  const int idxR = r_sp[base + q];
  const int idxE = e_sp[base + q];
  const int idxT = t_id[base + q];
  const int mk = amask[base + q];
  unsigned int mbits =
      (unsigned int)(__ballot(mk != 0) & 0xFFFFULL);  // bit i: action i active

  const int lc = lane < 50 ? lane : 49;  // clamped float4 index within row

  float pv = 0.0f;  // lane (r,q): row-r partial of action q

  if (mbits) {
    int i0 = __builtin_ctz(mbits);
    mbits &= mbits - 1;
    float4 vr = *reinterpret_cast<const float4*>(
        rel + (size_t)__builtin_amdgcn_readlane(idxR, i0) * DD + 4 * lc);
    float4 ve = *reinterpret_cast<const float4*>(
        entt + (size_t)__builtin_amdgcn_readlane(idxE, i0) * DD + 4 * lc);
    float4 vt = *reinterpret_cast<const float4*>(
        trip + (size_t)__builtin_amdgcn_readlane(idxT, i0) * DD + 4 * lc);

    while (mbits) {
      const int i1 = __builtin_ctz(mbits);
      mbits &= mbits - 1;
      const float4 nr = *reinterpret_cast<const float4*>(
          rel + (size_t)__builtin_amdgcn_readlane(idxR, i1) * DD + 4 * lc);
      const float4 ne = *reinterpret_cast<const float4*>(
          entt + (size_t)__builtin_amdgcn_readlane(idxE, i1) * DD + 4 * lc);
      const float4 nt = *reinterpret_cast<const float4*>(
          trip + (size_t)__builtin_amdgcn_readlane(idxT, i1) * DD + 4 * lc);

      float p = fmaf(vr.x, xr.x, fmaf(vr.y, xr.y, fmaf(vr.z, xr.z, vr.w * xr.w)));
      p = fmaf(ve.x, xe.x, fmaf(ve.y, xe.y, fmaf(ve.z, xe.z, fmaf(ve.w, xe.w, p))));
      p = fmaf(vt.x, xt.x, fmaf(vt.y, xt.y, fmaf(vt.z, xt.z, fmaf(vt.w, xt.w, p))));
      p = rot_add<0x128>(p);
      p = rot_add<0x124>(p);
      p = rot_add<0x122>(p);
      p = rot_add<0x121>(p);
      pv = (q == i0) ? p + pv : pv;

      vr = nr; ve = ne; vt = nt;
      i0 = i1;
    }

    float p = fmaf(vr.x, xr.x, fmaf(vr.y, xr.y, fmaf(vr.z, xr.z, vr.w * xr.w)));
    p = fmaf(ve.x, xe.x, fmaf(ve.y, xe.y, fmaf(ve.z, xe.z, fmaf(ve.w, xe.w, p))));
    p = fmaf(vt.x, xt.x, fmaf(vt.y, xt.y, fmaf(vt.z, xt.z, fmaf(vt.w, xt.w, p))));
    p = rot_add<0x128>(p);
    p = rot_add<0x124>(p);
    p = rot_add<0x122>(p);
    p = rot_add<0x121>(p);
    pv = (q == i0) ? p + pv : pv;
  }

  const float u1 = pv + __shfl_xor(pv, 16);
  const float u2 = u1 + __shfl_xor(u1, 32);  // all lanes: total for action (lane&15)

  if (lane < 16) {
    logits[base + lane] = mk ? u2 : -1e31f;
  }

  // ---- fused softmax: last block of the row does it ----
  __threadfence();          // release: make this block's logits device-visible
  __syncthreads();
  if (tid == 0) {
    const int old = atomicAdd(&counters[b], 1);
    s_last = (old == 7) ? 1 : 0;
  }
  __syncthreads();
  if (!s_last) return;
  __threadfence();          // acquire: see all 8 blocks' logits

  const float* lrow = logits + b * AA;
  const float l0 = lrow[tid];
  const float l1 = lrow[tid + 256];

  float m = fmaxf(l0, l1);
#pragma unroll
  for (int o = 32; o > 0; o >>= 1) m = fmaxf(m, __shfl_xor(m, o));
  if (lane == 0) s_red[tid >> 6] = m;
  __syncthreads();
  const float bm = fmaxf(fmaxf(s_red[0], s_red[1]), fmaxf(s_red[2], s_red[3]));

  const float e0 = __expf(l0 - bm);
  const float e1 = __expf(l1 - bm);
  float s = e0 + e1;
#pragma unroll
  for (int o = 32; o > 0; o >>= 1) s += __shfl_xor(s, o);
  __syncthreads();
  if (lane == 0) s_red[tid >> 6] = s;
  __syncthreads();
  const float bs = (s_red[0] + s_red[1]) + (s_red[2] + s_red[3]);

  const float p0 = e0 / bs;
  const float p1 = e1 / bs;
  out_dist[b * AA + tid] = p0;
  out_dist[b * AA + tid + 256] = p1;

  const float EPS = 2.220446049250313e-16f;
  float t = -p0 * __logf(p0 + EPS) - p1 * __logf(p1 + EPS);
#pragma unroll
  for (int o = 32; o > 0; o >>= 1) t += __shfl_xor(t, o);
  __syncthreads();
  if (lane == 0) s_red[tid >> 6] = t;
  __syncthreads();
  if (tid == 0)
    out_ent[b] = (s_red[0] + s_red[1]) + (s_red[2] + s_red[3]);
}

extern "C" void kernel_launch(void* const* d_in, const int* in_sizes, int n_in,
                              void* d_out, int out_size, void* d_ws, size_t ws_size,
                              hipStream_t stream) {
  const float* obs  = (const float*)d_in[0];
  const float* W1   = (const float*)d_in[1];
  const float* b1   = (const float*)d_in[2];
  const float* W2   = (const float*)d_in[3];
  const float* b2   = (const float*)d_in[4];
  const float* rel  = (const float*)d_in[5];
  const float* entt = (const float*)d_in[6];
  const float* trip = (const float*)d_in[7];
  const int* r_sp   = (const int*)d_in[8];
  const int* e_sp   = (const int*)d_in[9];
  const int* t_id   = (const int*)d_in[10];
  const int* amask  = (const int*)d_in[11];

  float* ws = (float*)d_ws;
  float* X1      = ws;                         // 153600 floats
  float* parts   = ws + BB * ADIM;             // 614400 floats
  float* X2      = ws + BB * ADIM * (1 + NKC); // 153600 floats
  float* logits  = ws + BB * ADIM * (2 + NKC); // 131072 floats
  int* counters  = (int*)(logits + BB * AA);   // 256 ints

  float* out = (float*)d_out;

  k_x1<<<128, 320, 0, stream>>>(obs, W1, b1, X1, counters);
  k_x2p<<<256, 640, 0, stream>>>(X1, W2, parts);
  k_x2<<<BB, 640, 0, stream>>>(parts, b2, X2);
  k_logits_soft<<<BB * 8, 256, 0, stream>>>(X2, rel, entt, trip, r_sp, e_sp,
                                            t_id, amask, logits, counters,
                                            out, out + BB * AA);
}

// Round 12
// 49.856 us; speedup vs baseline: 6.4347x; 6.4347x over previous
//
#include <hip/hip_runtime.h>
#include <hip/hip_bf16.h>

#define BB 256
#define AA 512
#define DD 200
#define ADIM 600
#define NKC 4
#define KCH 150   // 600 / 4

// ws layout (floats):
//   X1     at 0       (256*600 = 153600)
//   X2     at 153600  (256*600 = 153600)
//   logits at 307200  (256*512 = 131072)

// X1 = relu(obs @ W1 + b1), one row per block (256 blocks, all CUs busy).
// Also initializes X2 row to b2 (k_x2p atomically accumulates onto it).
__global__ __launch_bounds__(320) void k_x1(const float* __restrict__ obs,
                                            const float* __restrict__ W1,
                                            const float* __restrict__ b1,
                                            const float* __restrict__ b2,
                                            float* __restrict__ X1,
                                            float* __restrict__ X2) {
  __shared__ __align__(16) float s_obs[DD];
  const int b = blockIdx.x;
  const int tid = threadIdx.x;
  for (int j = tid; j < ADIM; j += 320) X2[b * ADIM + j] = b2[j];
  if (tid < 50) {  // 200 floats = 50 float4
    reinterpret_cast<float4*>(s_obs)[tid] =
        reinterpret_cast<const float4*>(obs + b * DD)[tid];
  }
  __syncthreads();

  const int jp = tid;
  if (jp < 300) {
    const int j0 = 2 * jp;
    float a0 = 0.f, a1 = 0.f;
#pragma unroll 5
    for (int kq = 0; kq < 50; ++kq) {
      const float4 x = *reinterpret_cast<const float4*>(&s_obs[kq * 4]);
      const float* wb = W1 + (kq * 4) * ADIM + j0;
      const float2 w0 = *reinterpret_cast<const float2*>(wb);
      const float2 w1 = *reinterpret_cast<const float2*>(wb + ADIM);
      const float2 w2 = *reinterpret_cast<const float2*>(wb + 2 * ADIM);
      const float2 w3 = *reinterpret_cast<const float2*>(wb + 3 * ADIM);
      a0 = fmaf(x.x, w0.x, a0); a1 = fmaf(x.x, w0.y, a1);
      a0 = fmaf(x.y, w1.x, a0); a1 = fmaf(x.y, w1.y, a1);
      a0 = fmaf(x.z, w2.x, a0); a1 = fmaf(x.z, w2.y, a1);
      a0 = fmaf(x.w, w3.x, a0); a1 = fmaf(x.w, w3.y, a1);
    }
    const float2 bv = *reinterpret_cast<const float2*>(b1 + j0);
    float2 o;
    o.x = fmaxf(a0 + bv.x, 0.f);
    o.y = fmaxf(a1 + bv.y, 0.f);
    *reinterpret_cast<float2*>(X1 + b * ADIM + j0) = o;
  }
}

// X2 += X1[kc-chunk] @ W2[kc-chunk] via f32 atomics (X2 pre-initialized to b2
// by k_x1; kernel boundary publishes the sums to k_logits — no fences needed).
__global__ __launch_bounds__(640) void k_x2p(const float* __restrict__ X1,
                                             const float* __restrict__ W2,
                                             float* __restrict__ X2) {
  __shared__ __align__(16) float s_x1[4 * 152];  // 150 used, stride 152
  const int rg = blockIdx.x >> 2;
  const int kc = blockIdx.x & 3;
  const int tid = threadIdx.x;
  const int kbase = kc * KCH;

  for (int idx = tid; idx < 4 * KCH; idx += 640) {
    const int r = idx / KCH, c = idx % KCH;
    s_x1[r * 152 + c] = X1[(rg * 4 + r) * ADIM + kbase + c];
  }
  __syncthreads();

  const int j = tid;
  if (j < ADIM) {
    float acc0 = 0.f, acc1 = 0.f, acc2 = 0.f, acc3 = 0.f;
#pragma unroll 4
    for (int kq = 0; kq < 37; ++kq) {  // 37*4 = 148 of 150
      const int k4 = kq * 4;
      const float4 x0 = *reinterpret_cast<const float4*>(&s_x1[0 * 152 + k4]);
      const float4 x1 = *reinterpret_cast<const float4*>(&s_x1[1 * 152 + k4]);
      const float4 x2 = *reinterpret_cast<const float4*>(&s_x1[2 * 152 + k4]);
      const float4 x3 = *reinterpret_cast<const float4*>(&s_x1[3 * 152 + k4]);
      const float* wb = W2 + (size_t)(kbase + k4) * ADIM + j;
      const float w0 = wb[0];
      const float w1 = wb[ADIM];
      const float w2 = wb[2 * ADIM];
      const float w3 = wb[3 * ADIM];
      acc0 = fmaf(x0.x, w0, fmaf(x0.y, w1, fmaf(x0.z, w2, fmaf(x0.w, w3, acc0))));
      acc1 = fmaf(x1.x, w0, fmaf(x1.y, w1, fmaf(x1.z, w2, fmaf(x1.w, w3, acc1))));
      acc2 = fmaf(x2.x, w0, fmaf(x2.y, w1, fmaf(x2.z, w2, fmaf(x2.w, w3, acc2))));
      acc3 = fmaf(x3.x, w0, fmaf(x3.y, w1, fmaf(x3.z, w2, fmaf(x3.w, w3, acc3))));
    }
#pragma unroll
    for (int kk = 148; kk < KCH; ++kk) {
      const float w = W2[(size_t)(kbase + kk) * ADIM + j];
      acc0 = fmaf(s_x1[0 * 152 + kk], w, acc0);
      acc1 = fmaf(s_x1[1 * 152 + kk], w, acc1);
      acc2 = fmaf(s_x1[2 * 152 + kk], w, acc2);
      acc3 = fmaf(s_x1[3 * 152 + kk], w, acc3);
    }
    float* xb = X2 + (size_t)(rg * 4) * ADIM + j;
    atomicAdd(&xb[0], acc0);
    atomicAdd(&xb[ADIM], acc1);
    atomicAdd(&xb[2 * ADIM], acc2);
    atomicAdd(&xb[3 * ADIM], acc3);
  }
}

// In-row (16-lane) rotate-add (DPP), no LDS-pipe traffic.
template <int CTRL>
__device__ inline float rot_add(float x) {
  const int xi = __float_as_int(x);
  const int r = __builtin_amdgcn_update_dpp(0, xi, CTRL, 0xF, 0xF, false);
  return x + __int_as_float(r);
}

// One wave = 16 actions of one batch row; masked actions contribute exactly
// -1e31 (f32 rounding absorbs the score) so their gathers are skipped.
// Dense ctz loop over set mask bits, depth-2 rotating load pipeline,
// full 6-waves/SIMD occupancy. (r10-identical.)
__global__ __launch_bounds__(256, 6) void k_logits(
    const float* __restrict__ X2, const float* __restrict__ rel,
    const float* __restrict__ entt, const float* __restrict__ trip,
    const int* __restrict__ r_sp, const int* __restrict__ e_sp,
    const int* __restrict__ t_id, const int* __restrict__ amask,
    float* __restrict__ logits) {
  const int b = blockIdx.x >> 3;
  const int c = blockIdx.x & 7;
  const int w = threadIdx.x >> 6;
  const int lane = threadIdx.x & 63;
  const int base = b * AA + c * 64 + w * 16;  // first of this wave's 16 actions

  // X2 segments -> registers; lane l holds floats [4l,4l+4) of each segment.
  float4 xr = {0.f, 0.f, 0.f, 0.f}, xe = xr, xt = xr;
  if (lane < 50) {
    const float* x2row = X2 + b * ADIM;
    xr = *reinterpret_cast<const float4*>(x2row + 4 * lane);
    xe = *reinterpret_cast<const float4*>(x2row + DD + 4 * lane);
    xt = *reinterpret_cast<const float4*>(x2row + 2 * DD + 4 * lane);
  }

  const int q = lane & 15;
  const int idxR = r_sp[base + q];
  const int idxE = e_sp[base + q];
  const int idxT = t_id[base + q];
  const int mk = amask[base + q];
  unsigned int mbits =
      (unsigned int)(__ballot(mk != 0) & 0xFFFFULL);  // bit i: action i active

  const int lc = lane < 50 ? lane : 49;  // clamped float4 index within row

  float pv = 0.0f;  // lane (r,q): row-r partial of action q

  if (mbits) {
    int i0 = __builtin_ctz(mbits);
    mbits &= mbits - 1;
    float4 vr = *reinterpret_cast<const float4*>(
        rel + (size_t)__builtin_amdgcn_readlane(idxR, i0) * DD + 4 * lc);
    float4 ve = *reinterpret_cast<const float4*>(
        entt + (size_t)__builtin_amdgcn_readlane(idxE, i0) * DD + 4 * lc);
    float4 vt = *reinterpret_cast<const float4*>(
        trip + (size_t)__builtin_amdgcn_readlane(idxT, i0) * DD + 4 * lc);

    while (mbits) {
      const int i1 = __builtin_ctz(mbits);
      mbits &= mbits - 1;
      const float4 nr = *reinterpret_cast<const float4*>(
          rel + (size_t)__builtin_amdgcn_readlane(idxR, i1) * DD + 4 * lc);
      const float4 ne = *reinterpret_cast<const float4*>(
          entt + (size_t)__builtin_amdgcn_readlane(idxE, i1) * DD + 4 * lc);
      const float4 nt = *reinterpret_cast<const float4*>(
          trip + (size_t)__builtin_amdgcn_readlane(idxT, i1) * DD + 4 * lc);

      float p = fmaf(vr.x, xr.x, fmaf(vr.y, xr.y, fmaf(vr.z, xr.z, vr.w * xr.w)));
      p = fmaf(ve.x, xe.x, fmaf(ve.y, xe.y, fmaf(ve.z, xe.z, fmaf(ve.w, xe.w, p))));
      p = fmaf(vt.x, xt.x, fmaf(vt.y, xt.y, fmaf(vt.z, xt.z, fmaf(vt.w, xt.w, p))));
      p = rot_add<0x128>(p);
      p = rot_add<0x124>(p);
      p = rot_add<0x122>(p);
      p = rot_add<0x121>(p);
      pv = (q == i0) ? p + pv : pv;

      vr = nr; ve = ne; vt = nt;
      i0 = i1;
    }

    float p = fmaf(vr.x, xr.x, fmaf(vr.y, xr.y, fmaf(vr.z, xr.z, vr.w * xr.w)));
    p = fmaf(ve.x, xe.x, fmaf(ve.y, xe.y, fmaf(ve.z, xe.z, fmaf(ve.w, xe.w, p))));
    p = fmaf(vt.x, xt.x, fmaf(vt.y, xt.y, fmaf(vt.z, xt.z, fmaf(vt.w, xt.w, p))));
    p = rot_add<0x128>(p);
    p = rot_add<0x124>(p);
    p = rot_add<0x122>(p);
    p = rot_add<0x121>(p);
    pv = (q == i0) ? p + pv : pv;
  }

  const float u1 = pv + __shfl_xor(pv, 16);
  const float u2 = u1 + __shfl_xor(u1, 32);  // all lanes: total for action (lane&15)

  if (lane < 16) {
    logits[base + lane] = mk ? u2 : -1e31f;
  }
}

__device__ inline float waveMax(float v) {
#pragma unroll
  for (int o = 32; o > 0; o >>= 1) v = fmaxf(v, __shfl_xor(v, o));
  return v;
}
__device__ inline float waveSum(float v) {
#pragma unroll
  for (int o = 32; o > 0; o >>= 1) v += __shfl_xor(v, o);
  return v;
}

__global__ __launch_bounds__(512) void k_soft(const float* __restrict__ logits,
                                              float* __restrict__ out_dist,
                                              float* __restrict__ out_ent) {
  __shared__ float s_red[8];
  const int b = blockIdx.x;
  const int tid = threadIdx.x;
  const float logit = logits[b * AA + tid];

  float m = waveMax(logit);
  if ((tid & 63) == 0) s_red[tid >> 6] = m;
  __syncthreads();
  float bm = s_red[0];
#pragma unroll
  for (int w = 1; w < 8; ++w) bm = fmaxf(bm, s_red[w]);
  __syncthreads();

  const float ev = __expf(logit - bm);
  float s = waveSum(ev);
  if ((tid & 63) == 0) s_red[tid >> 6] = s;
  __syncthreads();
  float bs = 0.0f;
#pragma unroll
  for (int w = 0; w < 8; ++w) bs += s_red[w];

  const float p = ev / bs;
  out_dist[b * AA + tid] = p;

  const float term = -p * __logf(p + 2.220446049250313e-16f);
  __syncthreads();
  float es = waveSum(term);
  if ((tid & 63) == 0) s_red[tid >> 6] = es;
  __syncthreads();
  if (tid == 0) {
    float etot = 0.0f;
#pragma unroll
    for (int w = 0; w < 8; ++w) etot += s_red[w];
    out_ent[b] = etot;
  }
}

extern "C" void kernel_launch(void* const* d_in, const int* in_sizes, int n_in,
                              void* d_out, int out_size, void* d_ws, size_t ws_size,
                              hipStream_t stream) {
  const float* obs  = (const float*)d_in[0];
  const float* W1   = (const float*)d_in[1];
  const float* b1   = (const float*)d_in[2];
  const float* W2   = (const float*)d_in[3];
  const float* b2   = (const float*)d_in[4];
  const float* rel  = (const float*)d_in[5];
  const float* entt = (const float*)d_in[6];
  const float* trip = (const float*)d_in[7];
  const int* r_sp   = (const int*)d_in[8];
  const int* e_sp   = (const int*)d_in[9];
  const int* t_id   = (const int*)d_in[10];
  const int* amask  = (const int*)d_in[11];

  float* ws = (float*)d_ws;
  float* X1     = ws;                 // 153600 floats
  float* X2     = ws + BB * ADIM;     // 153600 floats
  float* logits = ws + 2 * BB * ADIM; // 131072 floats

  float* out = (float*)d_out;

  k_x1<<<BB, 320, 0, stream>>>(obs, W1, b1, b2, X1, X2);
  k_x2p<<<256, 640, 0, stream>>>(X1, W2, X2);
  k_logits<<<BB * 8, 256, 0, stream>>>(X2, rel, entt, trip, r_sp, e_sp,
                                       t_id, amask, logits);
  k_soft<<<BB, 512, 0, stream>>>(logits, out, out + BB * AA);
}

// Round 13
// 49.431 us; speedup vs baseline: 6.4901x; 1.0086x over previous
//
#include <hip/hip_runtime.h>
#include <hip/hip_bf16.h>

#define BB 256
#define AA 512
#define DD 200
#define ADIM 600
#define NKC 4
#define KCH 150   // 600 / 4

// ws layout (floats): parts[4][256][600] at 0 (614400 floats)

// Fused MLP: block (rg, kc) computes its own X1 slice (4 rows x 150 cols,
// relu(obs@W1+b1)) into LDS, then the split-k W2 partial into parts[kc].
// No cross-block dependency; parts fully overwritten (no init needed).
__global__ __launch_bounds__(640) void k_mlp(const float* __restrict__ obs,
                                             const float* __restrict__ W1,
                                             const float* __restrict__ b1,
                                             const float* __restrict__ W2,
                                             float* __restrict__ parts) {
  __shared__ __align__(16) float s_obs[4 * DD];    // 4 rows of obs
  __shared__ __align__(16) float s_x1[4 * 152];    // X1 slice, padded stride
  const int rg = blockIdx.x >> 2;
  const int kc = blockIdx.x & 3;
  const int tid = threadIdx.x;
  const int kbase = kc * KCH;

  // 4 contiguous obs rows = 800 floats = 200 float4, coalesced
  if (tid < 200) {
    reinterpret_cast<float4*>(s_obs)[tid] =
        reinterpret_cast<const float4*>(obs + (size_t)rg * 4 * DD)[tid];
  }
  __syncthreads();

  // X1 slice: thread -> (r = tid/150, k = tid%150), col = kbase + k.
  // W1 reads coalesced across k; s_obs reads are wave-broadcast.
  if (tid < 600) {
    const int r = tid / KCH;
    const int k = tid - r * KCH;
    const int jcol = kbase + k;
    float a = b1[jcol];
    const float* srow = s_obs + r * DD;
#pragma unroll 8
    for (int kk = 0; kk < DD; ++kk) {
      a = fmaf(srow[kk], W1[kk * ADIM + jcol], a);
    }
    s_x1[r * 152 + k] = fmaxf(a, 0.0f);
  }
  __syncthreads();

  // parts[kc][rg*4+r][j] = X1slice[r][:] @ W2[kbase: kbase+150][j]
  const int j = tid;
  if (j < ADIM) {
    float acc0 = 0.f, acc1 = 0.f, acc2 = 0.f, acc3 = 0.f;
#pragma unroll 4
    for (int kq = 0; kq < 37; ++kq) {  // 37*4 = 148 of 150
      const int k4 = kq * 4;
      const float4 x0 = *reinterpret_cast<const float4*>(&s_x1[0 * 152 + k4]);
      const float4 x1 = *reinterpret_cast<const float4*>(&s_x1[1 * 152 + k4]);
      const float4 x2 = *reinterpret_cast<const float4*>(&s_x1[2 * 152 + k4]);
      const float4 x3 = *reinterpret_cast<const float4*>(&s_x1[3 * 152 + k4]);
      const float* wb = W2 + (size_t)(kbase + k4) * ADIM + j;
      const float w0 = wb[0];
      const float w1 = wb[ADIM];
      const float w2 = wb[2 * ADIM];
      const float w3 = wb[3 * ADIM];
      acc0 = fmaf(x0.x, w0, fmaf(x0.y, w1, fmaf(x0.z, w2, fmaf(x0.w, w3, acc0))));
      acc1 = fmaf(x1.x, w0, fmaf(x1.y, w1, fmaf(x1.z, w2, fmaf(x1.w, w3, acc1))));
      acc2 = fmaf(x2.x, w0, fmaf(x2.y, w1, fmaf(x2.z, w2, fmaf(x2.w, w3, acc2))));
      acc3 = fmaf(x3.x, w0, fmaf(x3.y, w1, fmaf(x3.z, w2, fmaf(x3.w, w3, acc3))));
    }
#pragma unroll
    for (int kk = 148; kk < KCH; ++kk) {
      const float w = W2[(size_t)(kbase + kk) * ADIM + j];
      acc0 = fmaf(s_x1[0 * 152 + kk], w, acc0);
      acc1 = fmaf(s_x1[1 * 152 + kk], w, acc1);
      acc2 = fmaf(s_x1[2 * 152 + kk], w, acc2);
      acc3 = fmaf(s_x1[3 * 152 + kk], w, acc3);
    }
    float* pb = parts + (size_t)kc * (BB * ADIM) + (size_t)(rg * 4) * ADIM + j;
    pb[0] = acc0;
    pb[ADIM] = acc1;
    pb[2 * ADIM] = acc2;
    pb[3 * ADIM] = acc3;
  }
}

// In-row (16-lane) rotate-add (DPP), no LDS-pipe traffic.
template <int CTRL>
__device__ inline float rot_add(float x) {
  const int xi = __float_as_int(x);
  const int r = __builtin_amdgcn_update_dpp(0, xi, CTRL, 0xF, 0xF, false);
  return x + __int_as_float(r);
}

// One block per batch row (512 thr, 8 waves). Wave w owns 64 actions,
// processed as 4 groups of 16 with the r12 depth-2 ctz gather. Logits land
// in LDS; after __syncthreads the same block does softmax+entropy.
// All producer->consumer is intra-block: no fences, no extra dispatches.
__global__ __launch_bounds__(512, 2) void k_logits_soft(
    const float* __restrict__ parts, const float* __restrict__ b2,
    const float* __restrict__ rel, const float* __restrict__ entt,
    const float* __restrict__ trip, const int* __restrict__ r_sp,
    const int* __restrict__ e_sp, const int* __restrict__ t_id,
    const int* __restrict__ amask, float* __restrict__ out_dist,
    float* __restrict__ out_ent) {
  __shared__ float s_logits[AA];
  __shared__ float s_red[8];
  const int b = blockIdx.x;
  const int tid = threadIdx.x;
  const int w = tid >> 6;
  const int lane = tid & 63;
  const int abase = b * AA + w * 64;  // wave's 64 actions

  // X2 segments -> registers: b2 + sum of 4 split-k partials (L2-hot),
  // amortized over the wave's 64 actions. Lane l holds floats [4l,4l+4).
  float4 xr = {0.f, 0.f, 0.f, 0.f}, xe = xr, xt = xr;
  if (lane < 50) {
    const int o0 = 4 * lane, o1 = DD + 4 * lane, o2 = 2 * DD + 4 * lane;
    xr = *reinterpret_cast<const float4*>(b2 + o0);
    xe = *reinterpret_cast<const float4*>(b2 + o1);
    xt = *reinterpret_cast<const float4*>(b2 + o2);
#pragma unroll
    for (int kc = 0; kc < NKC; ++kc) {
      const float* pr = parts + (size_t)kc * (BB * ADIM) + (size_t)b * ADIM;
      const float4 p0 = *reinterpret_cast<const float4*>(pr + o0);
      const float4 p1 = *reinterpret_cast<const float4*>(pr + o1);
      const float4 p2 = *reinterpret_cast<const float4*>(pr + o2);
      xr.x += p0.x; xr.y += p0.y; xr.z += p0.z; xr.w += p0.w;
      xe.x += p1.x; xe.y += p1.y; xe.z += p1.z; xe.w += p1.w;
      xt.x += p2.x; xt.y += p2.y; xt.z += p2.z; xt.w += p2.w;
    }
  }

  // per-lane indices/mask for the wave's 64 actions (coalesced loads)
  const int idxR = r_sp[abase + lane];
  const int idxE = e_sp[abase + lane];
  const int idxT = t_id[abase + lane];
  const int mk = amask[abase + lane];
  const unsigned long long mbits = __ballot(mk != 0);  // bit l = action l active

  const int q = lane & 15;
  const int lc = lane < 50 ? lane : 49;  // clamped float4 index within row

#pragma unroll
  for (int g = 0; g < 4; ++g) {
    unsigned int gm = (unsigned int)((mbits >> (g * 16)) & 0xFFFFULL);
    float pv = 0.0f;
    if (gm) {
      int i0 = __builtin_ctz(gm);
      gm &= gm - 1;
      float4 vr = *reinterpret_cast<const float4*>(
          rel + (size_t)__builtin_amdgcn_readlane(idxR, g * 16 + i0) * DD + 4 * lc);
      float4 ve = *reinterpret_cast<const float4*>(
          entt + (size_t)__builtin_amdgcn_readlane(idxE, g * 16 + i0) * DD + 4 * lc);
      float4 vt = *reinterpret_cast<const float4*>(
          trip + (size_t)__builtin_amdgcn_readlane(idxT, g * 16 + i0) * DD + 4 * lc);

      while (gm) {
        const int i1 = __builtin_ctz(gm);
        gm &= gm - 1;
        const float4 nr = *reinterpret_cast<const float4*>(
            rel + (size_t)__builtin_amdgcn_readlane(idxR, g * 16 + i1) * DD + 4 * lc);
        const float4 ne = *reinterpret_cast<const float4*>(
            entt + (size_t)__builtin_amdgcn_readlane(idxE, g * 16 + i1) * DD + 4 * lc);
        const float4 nt = *reinterpret_cast<const float4*>(
            trip + (size_t)__builtin_amdgcn_readlane(idxT, g * 16 + i1) * DD + 4 * lc);

        float p = fmaf(vr.x, xr.x, fmaf(vr.y, xr.y, fmaf(vr.z, xr.z, vr.w * xr.w)));
        p = fmaf(ve.x, xe.x, fmaf(ve.y, xe.y, fmaf(ve.z, xe.z, fmaf(ve.w, xe.w, p))));
        p = fmaf(vt.x, xt.x, fmaf(vt.y, xt.y, fmaf(vt.z, xt.z, fmaf(vt.w, xt.w, p))));
        p = rot_add<0x128>(p);
        p = rot_add<0x124>(p);
        p = rot_add<0x122>(p);
        p = rot_add<0x121>(p);
        pv = (q == i1) ? pv : ((q == i0) ? p + pv : pv);

        vr = nr; ve = ne; vt = nt;
        i0 = i1;
      }

      float p = fmaf(vr.x, xr.x, fmaf(vr.y, xr.y, fmaf(vr.z, xr.z, vr.w * xr.w)));
      p = fmaf(ve.x, xe.x, fmaf(ve.y, xe.y, fmaf(ve.z, xe.z, fmaf(ve.w, xe.w, p))));
      p = fmaf(vt.x, xt.x, fmaf(vt.y, xt.y, fmaf(vt.z, xt.z, fmaf(vt.w, xt.w, p))));
      p = rot_add<0x128>(p);
      p = rot_add<0x124>(p);
      p = rot_add<0x122>(p);
      p = rot_add<0x121>(p);
      pv = (q == i0) ? p + pv : pv;
    }

    // combine 4 row-partials; every lane then holds action (g*16 + q)'s total
    const float u1 = pv + __shfl_xor(pv, 16);
    const float u2 = u1 + __shfl_xor(u1, 32);
    if (lane < 16) {
      const int active = (int)((mbits >> (g * 16 + lane)) & 1ULL);
      s_logits[w * 64 + g * 16 + lane] = active ? u2 : -1e31f;
    }
  }

  __syncthreads();

  // ---- softmax + entropy over the row's 512 logits (in LDS) ----
  const float logit = s_logits[tid];

  float m = logit;
#pragma unroll
  for (int o = 32; o > 0; o >>= 1) m = fmaxf(m, __shfl_xor(m, o));
  if (lane == 0) s_red[w] = m;
  __syncthreads();
  float bm = s_red[0];
#pragma unroll
  for (int i = 1; i < 8; ++i) bm = fmaxf(bm, s_red[i]);
  __syncthreads();

  const float ev = __expf(logit - bm);
  float s = ev;
#pragma unroll
  for (int o = 32; o > 0; o >>= 1) s += __shfl_xor(s, o);
  if (lane == 0) s_red[w] = s;
  __syncthreads();
  float bs = 0.0f;
#pragma unroll
  for (int i = 0; i < 8; ++i) bs += s_red[i];

  const float p = ev / bs;
  out_dist[b * AA + tid] = p;

  const float term = -p * __logf(p + 2.220446049250313e-16f);
  __syncthreads();
  float es = term;
#pragma unroll
  for (int o = 32; o > 0; o >>= 1) es += __shfl_xor(es, o);
  if (lane == 0) s_red[w] = es;
  __syncthreads();
  if (tid == 0) {
    float etot = 0.0f;
#pragma unroll
    for (int i = 0; i < 8; ++i) etot += s_red[i];
    out_ent[b] = etot;
  }
}

extern "C" void kernel_launch(void* const* d_in, const int* in_sizes, int n_in,
                              void* d_out, int out_size, void* d_ws, size_t ws_size,
                              hipStream_t stream) {
  const float* obs  = (const float*)d_in[0];
  const float* W1   = (const float*)d_in[1];
  const float* b1   = (const float*)d_in[2];
  const float* W2   = (const float*)d_in[3];
  const float* b2   = (const float*)d_in[4];
  const float* rel  = (const float*)d_in[5];
  const float* entt = (const float*)d_in[6];
  const float* trip = (const float*)d_in[7];
  const int* r_sp   = (const int*)d_in[8];
  const int* e_sp   = (const int*)d_in[9];
  const int* t_id   = (const int*)d_in[10];
  const int* amask  = (const int*)d_in[11];

  float* parts = (float*)d_ws;  // 4*256*600 floats

  float* out = (float*)d_out;

  k_mlp<<<256, 640, 0, stream>>>(obs, W1, b1, W2, parts);
  k_logits_soft<<<BB, 512, 0, stream>>>(parts, b2, rel, entt, trip, r_sp,
                                        e_sp, t_id, amask, out, out + BB * AA);
}